// Round 8
// baseline (257.993 us; speedup 1.0000x reference)
//
#include <hip/hip_runtime.h>

#define GROUPSIZE 128
#define IN_F 4096
#define OUT_F 11008
#define TOKENS 512
#define N_GROUPS (OUT_F * IN_F / GROUPSIZE)  // 352256
#define NGK (IN_F / GROUPSIZE)               // 32

#define BM 64
#define BN 128
#define BK 64
#define NTHREADS 256
#define NT_G (IN_F / BK)      // 64
#define NT_H (NT_G / 2)       // 32 per k-half (split-K x2)
#define NTILES_N (OUT_F / BN) // 86

// workspace layout
#define WS_SZT_OFF ((size_t)TOKENS * IN_F * 2)              // x16: 4 MiB
#define WS_PQ_OFF  (WS_SZT_OFF + (size_t)N_GROUPS * 8)      // szt: 2.75 MB
#define WS_NEEDED  (WS_PQ_OFF + (size_t)OUT_F * IN_F / 2)   // pq: 22.5 MB

typedef _Float16 half8  __attribute__((ext_vector_type(8)));
typedef _Float16 half2v __attribute__((ext_vector_type(2)));
typedef float    f32x4  __attribute__((ext_vector_type(4)));
typedef int      ivec4  __attribute__((ext_vector_type(4)));

// issue-order fence: vmem ops may not be reordered across this by the compiler
#define MEMFENCE() asm volatile("" ::: "memory")

// A-tile halfword swizzle ([64 rows][64 hw], 128B rows): XOR 16B-granule by
// row&7 -> conflict-free ds_read_b128 frags (verified R1-R5).
__device__ __forceinline__ int swz(int r, int k) {
    return ((r << 6) + k) ^ ((r & 7) << 3);
}

__device__ __forceinline__ void glds16(const _Float16* g, _Float16* l) {
    __builtin_amdgcn_global_load_lds(
        (const __attribute__((address_space(1))) void*)g,
        (__attribute__((address_space(3))) void*)l, 16, 0, 0);
}

// pack 4 int32 "bytes" -> 1 dword (8 weights, 4-bit density): 3 v_perm (R5, verified)
__device__ __forceinline__ unsigned pack4(ivec4 q) {
    unsigned p01 = __builtin_amdgcn_perm((unsigned)q[1], (unsigned)q[0], 0x0C0C0400u);
    unsigned p23 = __builtin_amdgcn_perm((unsigned)q[3], (unsigned)q[2], 0x0C0C0400u);
    return __builtin_amdgcn_perm(p23, p01, 0x05040100u);
}

// dequant packed dword (8 weights) -> half8 via perm + pk_fma (R5, verified)
__device__ __forceinline__ half8 dqp(unsigned p, uint2 sz) {
    unsigned A4 = (p << 4) & 0xF0F0F0F0u;
    unsigned Bn =  p       & 0xF0F0F0F0u;
    unsigned t01 = __builtin_amdgcn_perm(A4, Bn, 0x05010400u);
    unsigned t23 = __builtin_amdgcn_perm(A4, Bn, 0x07030602u);
    const unsigned k54 = 0x54545454u;
    unsigned u0 = __builtin_amdgcn_perm(t01, k54, 0x00050004u);
    unsigned u1 = __builtin_amdgcn_perm(t01, k54, 0x00070006u);
    unsigned u2 = __builtin_amdgcn_perm(t23, k54, 0x00050004u);
    unsigned u3 = __builtin_amdgcn_perm(t23, k54, 0x00070006u);
    half2v S  = __builtin_bit_cast(half2v, sz.x);
    half2v Bv = __builtin_bit_cast(half2v, sz.y);
    union { half8 h; half2v p2[4]; } r;
    r.p2[0] = __builtin_bit_cast(half2v, u0) * S + Bv;
    r.p2[1] = __builtin_bit_cast(half2v, u1) * S + Bv;
    r.p2[2] = __builtin_bit_cast(half2v, u2) * S + Bv;
    r.p2[3] = __builtin_bit_cast(half2v, u3) * S + Bv;
    return r.h;
}

// ---------- pre-kernel 1: x fp32 -> fp16 ----------
__global__ __launch_bounds__(256)
void cvt_x_kernel(const float* __restrict__ x, _Float16* __restrict__ x16) {
    size_t i = ((size_t)blockIdx.x * 256 + threadIdx.x) * 8;
    f32x4 a = *(const f32x4*)(x + i);
    f32x4 b = *(const f32x4*)(x + i + 4);
    half8 h;
    h[0]=(_Float16)a[0]; h[1]=(_Float16)a[1]; h[2]=(_Float16)a[2]; h[3]=(_Float16)a[3];
    h[4]=(_Float16)b[0]; h[5]=(_Float16)b[1]; h[6]=(_Float16)b[2]; h[7]=(_Float16)b[3];
    *(half8*)(x16 + i) = h;
}

// ---------- pre-kernel 2: (S, -(64+z)*S) fp16 pairs, transposed [gk][row] ----------
__global__ __launch_bounds__(256)
void szpack_kernel(const float* __restrict__ s, const float* __restrict__ z,
                   uint2* __restrict__ szt) {
    int g = blockIdx.x * 256 + threadIdx.x;
    if (g >= N_GROUPS) return;
    int row = g / NGK, gk = g % NGK;
    _Float16 S = (_Float16)s[g];
    _Float16 B = (_Float16)(-(64.0f + z[g]) * (float)S);
    unsigned short su = __builtin_bit_cast(unsigned short, S);
    unsigned short bu = __builtin_bit_cast(unsigned short, B);
    uint2 r;
    r.x = ((unsigned)su << 16) | su;
    r.y = ((unsigned)bu << 16) | bu;
    szt[(size_t)gk * OUT_F + row] = r;
}

// ---------- pre-kernel 3: out = bias ----------
__global__ __launch_bounds__(256)
void out_init_kernel(const float* __restrict__ bias, float* __restrict__ out) {
    size_t i = ((size_t)blockIdx.x * 256 + threadIdx.x) * 4;
    int col = (int)(i % OUT_F);
    *(f32x4*)(out + i) = *(const f32x4*)(bias + col);
}

// ---------- pre-kernel 4: repack q to dense consumer-native layout ----------
// P dword index = (nt*64+ts)*1024 + ln4*256 + row*2 + kk
__global__ __launch_bounds__(256)
void repack_q_kernel(const int* __restrict__ qw, unsigned* __restrict__ pq) {
    unsigned tg = blockIdx.x * 256 + threadIdx.x;          // coalesced source order
    ivec4 q = *(const ivec4*)(qw + (size_t)tg * 4);
    unsigned ln4 = tg & 3, kk = (tg >> 2) & 1, ts = (tg >> 3) & 63;
    unsigned row_g = tg >> 9;
    unsigned nt = row_g >> 7, row = row_g & 127;
    size_t O = ((size_t)(nt * 64 + ts)) * 1024 + ln4 * 256 + row * 2 + kk;
    pq[O] = pack4(q);
}

template <int PACKED>
__global__ __launch_bounds__(NTHREADS, 5)
void qlinear_main(const _Float16* __restrict__ x16,
                  const void*  __restrict__ qsrc,
                  const uint2* __restrict__ szt,
                  float*       __restrict__ out)
{
    __shared__ __align__(16) _Float16 As[2][BM * BK];   // 2 x 8 KB only

    // XCD-local: bid&7 = XCD; each XCD owns 11 n-tiles x (8 m x 2 kh)
    const int bid = blockIdx.x;
    const int xcd = bid & 7;
    const int sgrp = bid >> 3;
    const int n_t = 11 * xcd + (sgrp >> 4);
    const int sub = sgrp & 15;
    const int m_t = sub & 7;
    const int kh  = sub >> 3;
    if (n_t >= NTILES_N) return;
    const int n0 = n_t * BN, m0 = m_t * BM;
    const int t0 = kh * NT_H;

    const int tid = threadIdx.x;
    const int wv = tid >> 6, ln = tid & 63;

    // A stager (glds, inverse-swizzled source)
    const int ar  = wv * 16 + (ln >> 3);
    const int gsw = (ln & 7) ^ ((ln >> 3) & 7);
    const _Float16* ag = x16 + (size_t)(m0 + ar) * IN_F + (size_t)t0 * BK + gsw * 8;

    // MFMA role: wave owns 64x32 (cols wc2..wc2+31)
    const int wc2 = wv * 32;
    const int lr = ln & 15, ln4 = ln >> 4, lk8 = ln4 * 8, lk4 = ln4 * 4;
    const int szrow = n0 + wc2 + lr;

    // q consumer pointers
    const uint2* qp0 = nullptr; const uint2* qp1 = nullptr;
    const int *qf0 = nullptr, *qf1 = nullptr, *qf2 = nullptr, *qf3 = nullptr;
    if constexpr (PACKED) {
        const unsigned* Pq = (const unsigned*)qsrc;
        size_t base = ((size_t)(n_t * 64 + t0)) * 1024 + (size_t)ln4 * 256
                    + (size_t)(wc2 + lr) * 2;
        qp0 = (const uint2*)(Pq + base);          // j=0 row; stride 1024 dw / ts
        qp1 = (const uint2*)(Pq + base + 32);     // j=1 row (+16 rows)
    } else {
        const int* qw = (const int*)qsrc;
        const int* b = qw + (size_t)(n0 + wc2 + lr) * (IN_F / 2)
                     + (size_t)t0 * 32 + ln4 * 4;
        qf0 = b; qf1 = b + 16;
        qf2 = b + (size_t)16 * (IN_F / 2); qf3 = qf2 + 16;
    }

    f32x4 acc[4][2];
#pragma unroll
    for (int i = 0; i < 4; ++i)
#pragma unroll
        for (int j = 0; j < 2; ++j)
            acc[i][j] = (f32x4){0.f, 0.f, 0.f, 0.f};

#define STAGE_A(tt, buf) do {                                      \
        const _Float16* gp = ag + (size_t)(tt) * 64;               \
        glds16(gp,            &As[buf][wv * 1024]);                \
        glds16(gp + 8 * IN_F, &As[buf][wv * 1024 + 512]);          \
        MEMFENCE();   /* pin: glds issued before subsequent loads */ \
    } while (0)

#define LOAD_QP(a0, a1, tt) do {                                   \
        a0 = qp0[(size_t)(tt) * 512]; a1 = qp1[(size_t)(tt) * 512]; \
    } while (0)

#define LOAD_QF(fr, tt) do {                                       \
        fr[0] = *(const ivec4*)(qf0 + (tt) * 32);                  \
        fr[1] = *(const ivec4*)(qf1 + (tt) * 32);                  \
        fr[2] = *(const ivec4*)(qf2 + (tt) * 32);                  \
        fr[3] = *(const ivec4*)(qf3 + (tt) * 32);                  \
    } while (0)

    auto mfma_phase = [&](int b, uint2 q0, uint2 q1,
                          ivec4 f0, ivec4 f1, ivec4 f2, ivec4 f3,
                          uint2 sz0, uint2 sz1) {
#pragma unroll
        for (int kk = 0; kk < 2; ++kk) {
            half8 af[4];
#pragma unroll
            for (int i = 0; i < 4; ++i)
                af[i] = *(const half8*)&As[b][swz(i * 16 + lr, kk * 32 + lk8)];
            unsigned p0, p1;
            if constexpr (PACKED) { p0 = kk ? q0.y : q0.x; p1 = kk ? q1.y : q1.x; }
            else { p0 = pack4(kk ? f1 : f0); p1 = pack4(kk ? f3 : f2); }
            half8 bf0 = dqp(p0, sz0);
#pragma unroll
            for (int i = 0; i < 4; ++i)
                acc[i][0] = __builtin_amdgcn_mfma_f32_16x16x32_f16(af[i], bf0, acc[i][0], 0, 0, 0);
            half8 bf1 = dqp(p1, sz1);
#pragma unroll
            for (int i = 0; i < 4; ++i)
                acc[i][1] = __builtin_amdgcn_mfma_f32_16x16x32_f16(af[i], bf1, acc[i][1], 0, 0, 0);
        }
    };

    // full drain before each barrier this round (diagnostic vs counted vmcnt)
#define WAITBAR() do {                                                   \
        asm volatile("s_waitcnt vmcnt(0) lgkmcnt(0)" ::: "memory");      \
        __builtin_amdgcn_s_barrier();                                    \
    } while (0)

    // ---- prologue ----
    uint2 qE0{}, qE1{}, qO0{}, qO1{};
    ivec4 fE[4] = {}, fO[4] = {};
    uint2 szc0, szc1, szn0, szn1;
    {
        const int gk0 = t0 >> 1;
        szc0 = szt[(size_t)gk0 * OUT_F + szrow];
        szc1 = szt[(size_t)gk0 * OUT_F + szrow + 16];
        STAGE_A(0, 0);
        if constexpr (PACKED) LOAD_QP(qE0, qE1, 0); else LOAD_QF(fE, 0);
        WAITBAR();
    }

    // ---- main loop: q/sz prefetch overlaps same-body MFMA; full drain at end ----
    for (int t = 0; t < NT_H; t += 2) {
        {   // even body: compute buf0 with qE (tiles t, t+1 share gk)
            STAGE_A(t + 1, 1);
            if constexpr (PACKED) LOAD_QP(qO0, qO1, t + 1); else LOAD_QF(fO, t + 1);
            mfma_phase(0, qE0, qE1, fE[0], fE[1], fE[2], fE[3], szc0, szc1);
            WAITBAR();
        }
        {   // odd body: compute buf1 with qO; prefetch sz for gk+1
            const int tn = (t + 2 < NT_H) ? t + 2 : NT_H - 1;
            STAGE_A(tn, 0);
            if constexpr (PACKED) LOAD_QP(qE0, qE1, tn); else LOAD_QF(fE, tn);
            const int gkn = (t0 + tn) >> 1;
            szn0 = szt[(size_t)gkn * OUT_F + szrow];
            szn1 = szt[(size_t)gkn * OUT_F + szrow + 16];
            mfma_phase(1, qO0, qO1, fO[0], fO[1], fO[2], fO[3], szc0, szc1);
            WAITBAR();
            szc0 = szn0; szc1 = szn1;
        }
    }

    // ---- epilogue: atomic accumulate (out pre-initialized to bias) ----
#pragma unroll
    for (int j = 0; j < 2; ++j) {
        const int col = n0 + wc2 + j * 16 + lr;
#pragma unroll
        for (int i = 0; i < 4; ++i) {
            const int rb = m0 + i * 16 + lk4;
#pragma unroll
            for (int r = 0; r < 4; ++r)
                atomicAdd(&out[(size_t)(rb + r) * OUT_F + col], acc[i][j][r]);
        }
    }
#undef STAGE_A
#undef LOAD_QP
#undef LOAD_QF
#undef WAITBAR
}

extern "C" void kernel_launch(void* const* d_in, const int* in_sizes, int n_in,
                              void* d_out, int out_size, void* d_ws, size_t ws_size,
                              hipStream_t stream) {
    const float* x      = (const float*)d_in[0];
    const int*   qw     = (const int*)d_in[1];
    const float* scales = (const float*)d_in[2];
    const float* zeros  = (const float*)d_in[3];
    const float* bias   = (const float*)d_in[4];
    float*       out    = (float*)d_out;

    char* ws = (char*)d_ws;
    _Float16* x16 = (_Float16*)ws;
    uint2*    szt = (uint2*)(ws + WS_SZT_OFF);

    cvt_x_kernel<<<TOKENS * IN_F / (256 * 8), 256, 0, stream>>>(x, x16);
    szpack_kernel<<<(N_GROUPS + 255) / 256, 256, 0, stream>>>(scales, zeros, szt);
    out_init_kernel<<<TOKENS * OUT_F / (256 * 4), 256, 0, stream>>>(bias, out);

    if (ws_size >= WS_NEEDED) {
        unsigned* pq = (unsigned*)(ws + WS_PQ_OFF);
        repack_q_kernel<<<(OUT_F * IN_F / 8) / 256, 256, 0, stream>>>(qw, pq);
        qlinear_main<1><<<1408, NTHREADS, 0, stream>>>(x16, pq, szt, out);
    } else {
        qlinear_main<0><<<1408, NTHREADS, 0, stream>>>(x16, qw, szt, out);
    }
}

// Round 9
// 249.676 us; speedup vs baseline: 1.0333x; 1.0333x over previous
//
#include <hip/hip_runtime.h>

#define GROUPSIZE 128
#define IN_F 4096
#define OUT_F 11008
#define TOKENS 512
#define N_GROUPS (OUT_F * IN_F / GROUPSIZE)  // 352256
#define NGK (IN_F / GROUPSIZE)               // 32

#define BM 64
#define BN 128
#define BK 64
#define NTHREADS 256
#define NT_G (IN_F / BK)      // 64
#define NT_H (NT_G / 2)       // 32 per k-half (split-K x2)
#define NTILES_N (OUT_F / BN) // 86

// workspace layout
#define WS_SZT_OFF ((size_t)TOKENS * IN_F * 2)              // x16: 4 MiB
#define WS_PQ_OFF  (WS_SZT_OFF + (size_t)N_GROUPS * 8)      // szt: 2.75 MB
#define WS_NEEDED  (WS_PQ_OFF + (size_t)OUT_F * IN_F / 2)   // pq: 22.5 MB

typedef _Float16 half8  __attribute__((ext_vector_type(8)));
typedef _Float16 half2v __attribute__((ext_vector_type(2)));
typedef float    f32x4  __attribute__((ext_vector_type(4)));
typedef int      ivec4  __attribute__((ext_vector_type(4)));

// issue-order fence: memory ops may not be reordered across this by the compiler
#define MEMFENCE() asm volatile("" ::: "memory")

// A-tile halfword swizzle ([64 rows][64 hw], 128B rows): XOR 16B-granule by
// row&7 -> conflict-free ds_read_b128 frags (verified R1-R8).
__device__ __forceinline__ int swz(int r, int k) {
    return ((r << 6) + k) ^ ((r & 7) << 3);
}

__device__ __forceinline__ void glds16(const _Float16* g, _Float16* l) {
    __builtin_amdgcn_global_load_lds(
        (const __attribute__((address_space(1))) void*)g,
        (__attribute__((address_space(3))) void*)l, 16, 0, 0);
}

// pack 4 int32 "bytes" -> 1 dword (8 weights, 4-bit density): 3 v_perm (R5, verified)
__device__ __forceinline__ unsigned pack4(ivec4 q) {
    unsigned p01 = __builtin_amdgcn_perm((unsigned)q[1], (unsigned)q[0], 0x0C0C0400u);
    unsigned p23 = __builtin_amdgcn_perm((unsigned)q[3], (unsigned)q[2], 0x0C0C0400u);
    return __builtin_amdgcn_perm(p23, p01, 0x05040100u);
}

// dequant packed dword (8 weights) -> half8 via perm + pk_fma (R5, verified)
__device__ __forceinline__ half8 dqp(unsigned p, uint2 sz) {
    unsigned A4 = (p << 4) & 0xF0F0F0F0u;
    unsigned Bn =  p       & 0xF0F0F0F0u;
    unsigned t01 = __builtin_amdgcn_perm(A4, Bn, 0x05010400u);
    unsigned t23 = __builtin_amdgcn_perm(A4, Bn, 0x07030602u);
    const unsigned k54 = 0x54545454u;
    unsigned u0 = __builtin_amdgcn_perm(t01, k54, 0x00050004u);
    unsigned u1 = __builtin_amdgcn_perm(t01, k54, 0x00070006u);
    unsigned u2 = __builtin_amdgcn_perm(t23, k54, 0x00050004u);
    unsigned u3 = __builtin_amdgcn_perm(t23, k54, 0x00070006u);
    half2v S  = __builtin_bit_cast(half2v, sz.x);
    half2v Bv = __builtin_bit_cast(half2v, sz.y);
    union { half8 h; half2v p2[4]; } r;
    r.p2[0] = __builtin_bit_cast(half2v, u0) * S + Bv;
    r.p2[1] = __builtin_bit_cast(half2v, u1) * S + Bv;
    r.p2[2] = __builtin_bit_cast(half2v, u2) * S + Bv;
    r.p2[3] = __builtin_bit_cast(half2v, u3) * S + Bv;
    return r.h;
}

// ---------- pre-kernel 1: x fp32 -> fp16 ----------
__global__ __launch_bounds__(256)
void cvt_x_kernel(const float* __restrict__ x, _Float16* __restrict__ x16) {
    size_t i = ((size_t)blockIdx.x * 256 + threadIdx.x) * 8;
    f32x4 a = *(const f32x4*)(x + i);
    f32x4 b = *(const f32x4*)(x + i + 4);
    half8 h;
    h[0]=(_Float16)a[0]; h[1]=(_Float16)a[1]; h[2]=(_Float16)a[2]; h[3]=(_Float16)a[3];
    h[4]=(_Float16)b[0]; h[5]=(_Float16)b[1]; h[6]=(_Float16)b[2]; h[7]=(_Float16)b[3];
    *(half8*)(x16 + i) = h;
}

// ---------- pre-kernel 2: (S, -(64+z)*S) fp16 pairs, transposed [gk][row] ----------
__global__ __launch_bounds__(256)
void szpack_kernel(const float* __restrict__ s, const float* __restrict__ z,
                   uint2* __restrict__ szt) {
    int g = blockIdx.x * 256 + threadIdx.x;
    if (g >= N_GROUPS) return;
    int row = g / NGK, gk = g % NGK;
    _Float16 S = (_Float16)s[g];
    _Float16 B = (_Float16)(-(64.0f + z[g]) * (float)S);
    unsigned short su = __builtin_bit_cast(unsigned short, S);
    unsigned short bu = __builtin_bit_cast(unsigned short, B);
    uint2 r;
    r.x = ((unsigned)su << 16) | su;
    r.y = ((unsigned)bu << 16) | bu;
    szt[(size_t)gk * OUT_F + row] = r;
}

// ---------- pre-kernel 3: out = bias ----------
__global__ __launch_bounds__(256)
void out_init_kernel(const float* __restrict__ bias, float* __restrict__ out) {
    size_t i = ((size_t)blockIdx.x * 256 + threadIdx.x) * 4;
    int col = (int)(i % OUT_F);
    *(f32x4*)(out + i) = *(const f32x4*)(bias + col);
}

// ---------- pre-kernel 4: repack q to dense consumer-native layout ----------
// P dword index = (nt*64+ts)*1024 + ln4*256 + row*2 + kk
__global__ __launch_bounds__(256)
void repack_q_kernel(const int* __restrict__ qw, unsigned* __restrict__ pq) {
    unsigned tg = blockIdx.x * 256 + threadIdx.x;          // coalesced source order
    ivec4 q = *(const ivec4*)(qw + (size_t)tg * 4);
    unsigned ln4 = tg & 3, kk = (tg >> 2) & 1, ts = (tg >> 3) & 63;
    unsigned row_g = tg >> 9;
    unsigned nt = row_g >> 7, row = row_g & 127;
    size_t O = ((size_t)(nt * 64 + ts)) * 1024 + ln4 * 256 + row * 2 + kk;
    pq[O] = pack4(q);
}

template <int PACKED>
__global__ __launch_bounds__(NTHREADS, 5)
void qlinear_main(const _Float16* __restrict__ x16,
                  const void*  __restrict__ qsrc,
                  const uint2* __restrict__ szt,
                  float*       __restrict__ out)
{
    __shared__ __align__(16) _Float16 As[2][BM * BK];   // 2 x 8 KB only

    // XCD-local: bid&7 = XCD; each XCD owns 11 n-tiles x (8 m x 2 kh)
    const int bid = blockIdx.x;
    const int xcd = bid & 7;
    const int sgrp = bid >> 3;
    const int n_t = 11 * xcd + (sgrp >> 4);
    const int sub = sgrp & 15;
    const int m_t = sub & 7;
    const int kh  = sub >> 3;
    if (n_t >= NTILES_N) return;
    const int n0 = n_t * BN, m0 = m_t * BM;
    const int t0 = kh * NT_H;

    const int tid = threadIdx.x;
    const int wv = tid >> 6, ln = tid & 63;

    // A stager (glds, inverse-swizzled source)
    const int ar  = wv * 16 + (ln >> 3);
    const int gsw = (ln & 7) ^ ((ln >> 3) & 7);
    const _Float16* ag = x16 + (size_t)(m0 + ar) * IN_F + (size_t)t0 * BK + gsw * 8;

    // MFMA role: wave owns 64x32 (cols wc2..wc2+31)
    const int wc2 = wv * 32;
    const int lr = ln & 15, ln4 = ln >> 4, lk8 = ln4 * 8, lk4 = ln4 * 4;
    const int szrow = n0 + wc2 + lr;

    // q consumer pointers
    const uint2* qp0 = nullptr; const uint2* qp1 = nullptr;
    const int *qf0 = nullptr, *qf1 = nullptr, *qf2 = nullptr, *qf3 = nullptr;
    if constexpr (PACKED) {
        const unsigned* Pq = (const unsigned*)qsrc;
        size_t base = ((size_t)(n_t * 64 + t0)) * 1024 + (size_t)ln4 * 256
                    + (size_t)(wc2 + lr) * 2;
        qp0 = (const uint2*)(Pq + base);          // j=0 row; stride 1024 dw / ts
        qp1 = (const uint2*)(Pq + base + 32);     // j=1 row (+16 rows)
    } else {
        const int* qw = (const int*)qsrc;
        const int* b = qw + (size_t)(n0 + wc2 + lr) * (IN_F / 2)
                     + (size_t)t0 * 32 + ln4 * 4;
        qf0 = b; qf1 = b + 16;
        qf2 = b + (size_t)16 * (IN_F / 2); qf3 = qf2 + 16;
    }

    f32x4 acc[4][2];
#pragma unroll
    for (int i = 0; i < 4; ++i)
#pragma unroll
        for (int j = 0; j < 2; ++j)
            acc[i][j] = (f32x4){0.f, 0.f, 0.f, 0.f};

#define STAGE_A(tt, buf) do {                                      \
        const _Float16* gp = ag + (size_t)(tt) * 64;               \
        glds16(gp,            &As[buf][wv * 1024]);                \
        glds16(gp + 8 * IN_F, &As[buf][wv * 1024 + 512]);          \
        MEMFENCE();   /* pin: glds issued before subsequent loads */ \
    } while (0)

#define LOAD_QP(a0, a1, tt) do {                                   \
        a0 = qp0[(size_t)(tt) * 512]; a1 = qp1[(size_t)(tt) * 512]; \
    } while (0)

#define LOAD_QF(fr, tt) do {                                       \
        fr[0] = *(const ivec4*)(qf0 + (tt) * 32);                  \
        fr[1] = *(const ivec4*)(qf1 + (tt) * 32);                  \
        fr[2] = *(const ivec4*)(qf2 + (tt) * 32);                  \
        fr[3] = *(const ivec4*)(qf3 + (tt) * 32);                  \
    } while (0)

    auto mfma_phase = [&](int b, uint2 q0, uint2 q1,
                          ivec4 f0, ivec4 f1, ivec4 f2, ivec4 f3,
                          uint2 sz0, uint2 sz1) {
#pragma unroll
        for (int kk = 0; kk < 2; ++kk) {
            half8 af[4];
#pragma unroll
            for (int i = 0; i < 4; ++i)
                af[i] = *(const half8*)&As[b][swz(i * 16 + lr, kk * 32 + lk8)];
            unsigned p0, p1;
            if constexpr (PACKED) { p0 = kk ? q0.y : q0.x; p1 = kk ? q1.y : q1.x; }
            else { p0 = pack4(kk ? f1 : f0); p1 = pack4(kk ? f3 : f2); }
            half8 bf0 = dqp(p0, sz0);
#pragma unroll
            for (int i = 0; i < 4; ++i)
                acc[i][0] = __builtin_amdgcn_mfma_f32_16x16x32_f16(af[i], bf0, acc[i][0], 0, 0, 0);
            half8 bf1 = dqp(p1, sz1);
#pragma unroll
            for (int i = 0; i < 4; ++i)
                acc[i][1] = __builtin_amdgcn_mfma_f32_16x16x32_f16(af[i], bf1, acc[i][1], 0, 0, 0);
        }
    };

    // counted-vmcnt barrier (T4): drain only this body's 2 A-glds (oldest,
    // order pinned by MEMFENCE); q/sz prefetches stay in flight across the
    // barrier and are drained by the compiler's register-dep wait at use.
#define WAITBAR_N(n) do {                                                \
        asm volatile("s_waitcnt vmcnt(" #n ") lgkmcnt(0)" ::: "memory"); \
        __builtin_amdgcn_s_barrier();                                    \
    } while (0)

    // ---- prologue (full drain) ----
    uint2 qE0{}, qE1{}, qO0{}, qO1{};
    ivec4 fE[4] = {}, fO[4] = {};
    uint2 szc0, szc1, szn0, szn1;
    {
        const int gk0 = t0 >> 1;
        szc0 = szt[(size_t)gk0 * OUT_F + szrow];
        szc1 = szt[(size_t)gk0 * OUT_F + szrow + 16];
        STAGE_A(0, 0);
        if constexpr (PACKED) LOAD_QP(qE0, qE1, 0); else LOAD_QF(fE, 0);
        WAITBAR_N(0);
    }

    // ---- main loop: q/sz prefetch stays in flight across the barrier ----
    for (int t = 0; t < NT_H; t += 2) {
        {   // even body: compute buf0 with qE (tiles t, t+1 share gk)
            STAGE_A(t + 1, 1);
            if constexpr (PACKED) LOAD_QP(qO0, qO1, t + 1); else LOAD_QF(fO, t + 1);
            mfma_phase(0, qE0, qE1, fE[0], fE[1], fE[2], fE[3], szc0, szc1);
            if constexpr (PACKED) WAITBAR_N(2); else WAITBAR_N(4);
        }
        {   // odd body: compute buf1 with qO; prefetch sz for gk+1
            const int tn = (t + 2 < NT_H) ? t + 2 : NT_H - 1;
            STAGE_A(tn, 0);
            if constexpr (PACKED) LOAD_QP(qE0, qE1, tn); else LOAD_QF(fE, tn);
            const int gkn = (t0 + tn) >> 1;
            szn0 = szt[(size_t)gkn * OUT_F + szrow];
            szn1 = szt[(size_t)gkn * OUT_F + szrow + 16];
            mfma_phase(1, qO0, qO1, fO[0], fO[1], fO[2], fO[3], szc0, szc1);
            if constexpr (PACKED) WAITBAR_N(4); else WAITBAR_N(6);
            szc0 = szn0; szc1 = szn1;
        }
    }

    // ---- epilogue: atomic accumulate (out pre-initialized to bias) ----
#pragma unroll
    for (int j = 0; j < 2; ++j) {
        const int col = n0 + wc2 + j * 16 + lr;
#pragma unroll
        for (int i = 0; i < 4; ++i) {
            const int rb = m0 + i * 16 + lk4;
#pragma unroll
            for (int r = 0; r < 4; ++r)
                atomicAdd(&out[(size_t)(rb + r) * OUT_F + col], acc[i][j][r]);
        }
    }
#undef STAGE_A
#undef LOAD_QP
#undef LOAD_QF
#undef WAITBAR_N
}

extern "C" void kernel_launch(void* const* d_in, const int* in_sizes, int n_in,
                              void* d_out, int out_size, void* d_ws, size_t ws_size,
                              hipStream_t stream) {
    const float* x      = (const float*)d_in[0];
    const int*   qw     = (const int*)d_in[1];
    const float* scales = (const float*)d_in[2];
    const float* zeros  = (const float*)d_in[3];
    const float* bias   = (const float*)d_in[4];
    float*       out    = (float*)d_out;

    char* ws = (char*)d_ws;
    _Float16* x16 = (_Float16*)ws;
    uint2*    szt = (uint2*)(ws + WS_SZT_OFF);

    cvt_x_kernel<<<TOKENS * IN_F / (256 * 8), 256, 0, stream>>>(x, x16);
    szpack_kernel<<<(N_GROUPS + 255) / 256, 256, 0, stream>>>(scales, zeros, szt);
    out_init_kernel<<<TOKENS * OUT_F / (256 * 4), 256, 0, stream>>>(bias, out);

    if (ws_size >= WS_NEEDED) {
        unsigned* pq = (unsigned*)(ws + WS_PQ_OFF);
        repack_q_kernel<<<(OUT_F * IN_F / 8) / 256, 256, 0, stream>>>(qw, pq);
        qlinear_main<1><<<1408, NTHREADS, 0, stream>>>(x16, pq, szt, out);
    } else {
        qlinear_main<0><<<1408, NTHREADS, 0, stream>>>(x16, qw, szt, out);
    }
}